// Round 6
// baseline (354.665 us; speedup 1.0000x reference)
//
#include <hip/hip_runtime.h>
#include <math.h>

typedef _Float16 half8 __attribute__((ext_vector_type(8)));
typedef float f32x4 __attribute__((ext_vector_type(4)));

#define BTOT   65536
#define DDIM   256
#define KC     1024

static __device__ __forceinline__ f32x4 nt_load4(const float* p) {
    return __builtin_nontemporal_load((const f32x4*)p);
}

// ---------------- ||e_k||^2 ----------------
__global__ void vq_e2(const float* __restrict__ embed, float* __restrict__ e2g) {
    int gt = blockIdx.x * blockDim.x + threadIdx.x;
    int k = gt >> 6;
    int lane = gt & 63;
    float4 v = *(const float4*)(embed + (size_t)k * DDIM + lane * 4);
    float s = v.x * v.x + v.y * v.y + v.z * v.z + v.w * v.w;
    #pragma unroll
    for (int off = 1; off < 64; off <<= 1) s += __shfl_xor(s, off);
    if (lane == 0) e2g[k] = s;
}

// ---------------- prep: embed -> fp16 hi/lo fragment-ordered image --------
// chunks of 1024B: chunk = (g*8 + kc)*2 + p   (g = col-group c>>4, kc = k>>5,
// p: 0=hi 1=lo). Lane l's 16B at l*16: col (c&15)=l&15 at (c&15)*16, k-slot
// s=(l>>4) at s*256.
__global__ void vq_prep(const float* __restrict__ embed, char* __restrict__ wsB) {
    int id = blockIdx.x * 256 + threadIdx.x;   // 32768 total
    int c  = id >> 5;          // 0..1023
    int kc = (id >> 2) & 7;    // 0..7
    int s  = id & 3;           // 0..3
    const float* src = embed + (size_t)c * DDIM + kc * 32 + s * 8;
    half8 hi, lo;
    #pragma unroll
    for (int j = 0; j < 8; ++j) {
        float xv = src[j];
        _Float16 hh = (_Float16)xv;
        hi[j] = hh;
        lo[j] = (_Float16)(xv - (float)hh);
    }
    int g = c >> 4;
    size_t base = ((size_t)((g * 8 + kc) * 2) << 10) + (c & 15) * 16 + s * 256;
    *(half8*)(wsB + base) = hi;
    *(half8*)(wsB + base + 1024) = lo;
}

// ---------------- main fused MFMA GEMM + softmax/argmax ----------------
// 512 threads (8 waves); block owns 32 rows x all 1024 cols; wave w owns cols
// [w*128, w*128+128). A (z) fp16 hi/lo in LDS (32KB); B streamed global->reg
// with 3-slot rolling prefetch. <=128 regs -> 2 blocks/CU for overlap.
__global__ __launch_bounds__(512, 4)
void vq_main(const float* __restrict__ z, const char* __restrict__ wsB,
             const float* __restrict__ e2g, float* __restrict__ psum_g,
             float* __restrict__ counts_g, float* __restrict__ distsum_g,
             float* __restrict__ codes_f_out)
{
    // A: [kc(8)][p(2)][row(32)][slot(4, xor-swizzled)] = 32KB
    __shared__ __align__(16) char ldsA[32768];
    // epilogue aliases (ldsA dead after K-loop):
    float* lmax     = (float*)ldsA;               // [32][8] 1KB
    int*   larg     = (int*)(ldsA + 1024);        // [32][8] 1KB
    float* lsum     = (float*)(ldsA + 2048);      // [32][8] 1KB
    float* rowM     = (float*)(ldsA + 3072);      // [32]
    float* rowInv   = (float*)(ldsA + 3200);      // [32]
    float* psum_lds = (float*)(ldsA + 4096);      // [1024] 4KB

    const int tid  = threadIdx.x;
    const int w    = tid >> 6;
    const int lane = tid & 63;
    const int row0 = blockIdx.x * 32;
    // A fragment base: row=(lane&15), k-slot=(lane>>4) xor-swizzled by row
    const int aBase = (lane & 15) * 64 + (((lane >> 4) ^ ((lane >> 1) & 3)) << 4);
    // per-wave B base: g = w*8+cg; byte = w*131072 + cg*16384 + kc*2048
    const char* wB = wsB + (size_t)w * 131072 + (lane << 4);

    half8 bh[3], bl[3];
    // t = kc*8 + cg (cg fastest). OFF(t) compile-time.
    #define BOFF(t) ((size_t)(((t) & 7) * 16384 + ((t) >> 3) * 2048))
    #define BLOAD(slot, t) do { \
        bh[slot] = *(const half8*)(wB + BOFF(t)); \
        bl[slot] = *(const half8*)(wB + BOFF(t) + 1024); } while (0)

    // preload t=0,1 (before staging: latency hidden under A staging)
    BLOAD(0, 0);
    BLOAD(1, 1);

    // ---- A staging: 32 rows of z -> fp16 hi/lo swizzled in LDS (NT loads) ----
    {
        const int ar = tid >> 4;     // row 0..31 (wave w covers rows 4w..4w+3)
        const int kp = tid & 15;     // 16-float k-part
        const float* src = z + (size_t)(row0 + ar) * DDIM + kp * 16;
        float x[16];
        #pragma unroll
        for (int j = 0; j < 4; ++j) {
            f32x4 v = nt_load4(src + 4 * j);
            x[4*j] = v[0]; x[4*j+1] = v[1]; x[4*j+2] = v[2]; x[4*j+3] = v[3];
        }
        float zsq = 0.f;
        #pragma unroll
        for (int j = 0; j < 16; ++j) zsq = fmaf(x[j], x[j], zsq);
        #pragma unroll
        for (int off = 1; off < 64; off <<= 1) zsq += __shfl_xor(zsq, off);
        if (lane == 0) atomicAdd(distsum_g, zsq);   // Σ||z||^2 (4 rows/wave)
        const int kc = kp >> 1;
        #pragma unroll
        for (int jj = 0; jj < 2; ++jj) {
            int s = (kp & 1) * 2 + jj;
            half8 hi, lo;
            #pragma unroll
            for (int j = 0; j < 8; ++j) {
                float xv = x[jj * 8 + j];
                _Float16 hh = (_Float16)xv;
                hi[j] = hh;
                lo[j] = (_Float16)(xv - (float)hh);
            }
            int off = kc * 4096 + ar * 64 + ((s ^ ((ar >> 1) & 3)) << 4);
            *(half8*)(ldsA + off) = hi;            // p=0
            *(half8*)(ldsA + 2048 + off) = lo;     // p=1
        }
    }
    __syncthreads();

    f32x4 acc[2][8];
    #pragma unroll
    for (int rt = 0; rt < 2; ++rt)
        #pragma unroll
        for (int cg = 0; cg < 8; ++cg)
            acc[rt][cg] = (f32x4){0.f, 0.f, 0.f, 0.f};

    half8 aHi[2], aLo[2];

    // ---- K-loop: 64 steps, barrier-free, depth-2 rolling B prefetch ----
    #pragma unroll
    for (int t = 0; t < 64; ++t) {
        if (t + 2 < 64) BLOAD((t + 2) % 3, t + 2);
        if ((t & 7) == 0) {             // new kc: load A frags from LDS
            const int kc = t >> 3;
            #pragma unroll
            for (int rt = 0; rt < 2; ++rt) {
                aHi[rt] = *(const half8*)(ldsA + kc * 4096 + rt * 1024 + aBase);
                aLo[rt] = *(const half8*)(ldsA + kc * 4096 + 2048 + rt * 1024 + aBase);
            }
        }
        const int cg = t & 7;
        half8 bH = bh[t % 3], bL = bl[t % 3];
        // per-acc product order: hi*bHi, lo*bHi, hi*bLo (kc ascending) —
        // identical numerics to verified R2-R4.
        acc[0][cg] = __builtin_amdgcn_mfma_f32_16x16x32_f16(aHi[0], bH, acc[0][cg], 0, 0, 0);
        acc[1][cg] = __builtin_amdgcn_mfma_f32_16x16x32_f16(aHi[1], bH, acc[1][cg], 0, 0, 0);
        acc[0][cg] = __builtin_amdgcn_mfma_f32_16x16x32_f16(aLo[0], bH, acc[0][cg], 0, 0, 0);
        acc[1][cg] = __builtin_amdgcn_mfma_f32_16x16x32_f16(aLo[1], bH, acc[1][cg], 0, 0, 0);
        acc[0][cg] = __builtin_amdgcn_mfma_f32_16x16x32_f16(aHi[0], bL, acc[0][cg], 0, 0, 0);
        acc[1][cg] = __builtin_amdgcn_mfma_f32_16x16x32_f16(aHi[1], bL, acc[1][cg], 0, 0, 0);
    }
    __syncthreads();   // ldsA dead -> reuse for epilogue

    // ---- epilogue ----
    // wave w cols: cg -> w*128 + cg*16 + (lane&15); C/D row = rt*16+(lane>>4)*4+i
    int colv[8];
    float e2v[8];
    #pragma unroll
    for (int cg = 0; cg < 8; ++cg) {
        colv[cg] = w * 128 + cg * 16 + (lane & 15);
        e2v[cg] = e2g[colv[cg]];
    }
    psum_lds[tid] = 0.f;
    psum_lds[tid + 512] = 0.f;
    // pass 1: per-wave local max/argmax per row
    #pragma unroll
    for (int rt = 0; rt < 2; ++rt) {
        #pragma unroll
        for (int i = 0; i < 4; ++i) {
            float m = -INFINITY; int am = 0x7fffffff;
            #pragma unroll
            for (int cg = 0; cg < 8; ++cg) {
                float l = fmaf(2.f, acc[rt][cg][i], -e2v[cg]);
                if (l > m) { m = l; am = colv[cg]; }
            }
            #pragma unroll
            for (int off = 1; off < 16; off <<= 1) {
                float om = __shfl_xor(m, off);
                int   oa = __shfl_xor(am, off);
                if (om > m || (om == m && oa < am)) { m = om; am = oa; }
            }
            if ((lane & 15) == 0) {
                int r = rt * 16 + ((lane >> 4) << 2) + i;
                lmax[r * 8 + w] = m; larg[r * 8 + w] = am;
            }
        }
    }
    __syncthreads();
    // pass 2: cross-wave reduce; codes, counts, -Σ(max logit)
    if (tid < 32) {
        float M = -INFINITY; int A = 0x7fffffff;
        #pragma unroll
        for (int ww = 0; ww < 8; ++ww) {
            float mm = lmax[tid * 8 + ww]; int aa = larg[tid * 8 + ww];
            if (mm > M || (mm == M && aa < A)) { M = mm; A = aa; }
        }
        rowM[tid] = M;
        codes_f_out[row0 + tid] = (float)A;
        atomicAdd(&counts_g[A], 1.0f);
        float negm = -M;
        #pragma unroll
        for (int off = 1; off < 32; off <<= 1) negm += __shfl_xor(negm, off);
        if (tid == 0) atomicAdd(distsum_g, negm);
    }
    __syncthreads();
    // pass 3: exp and per-wave row sums
    #pragma unroll
    for (int rt = 0; rt < 2; ++rt) {
        #pragma unroll
        for (int i = 0; i < 4; ++i) {
            const int r = rt * 16 + ((lane >> 4) << 2) + i;
            float M = rowM[r];
            float ss = 0.f;
            #pragma unroll
            for (int cg = 0; cg < 8; ++cg) {
                float e = __expf(fmaf(2.f, acc[rt][cg][i], -e2v[cg]) - M);
                acc[rt][cg][i] = e;
                ss += e;
            }
            #pragma unroll
            for (int off = 1; off < 16; off <<= 1) ss += __shfl_xor(ss, off);
            if ((lane & 15) == 0) lsum[r * 8 + w] = ss;
        }
    }
    __syncthreads();
    // pass 4: row denominators
    if (tid < 32) {
        float S = 0.f;
        #pragma unroll
        for (int ww = 0; ww < 8; ++ww) S += lsum[tid * 8 + ww];
        rowInv[tid] = 1.0f / S;
    }
    __syncthreads();
    // pass 5: per-code prob sums
    #pragma unroll
    for (int cg = 0; cg < 8; ++cg) {
        float cp = 0.f;
        #pragma unroll
        for (int rt = 0; rt < 2; ++rt)
            #pragma unroll
            for (int i = 0; i < 4; ++i)
                cp = fmaf(acc[rt][cg][i], rowInv[rt * 16 + ((lane >> 4) << 2) + i], cp);
        atomicAdd(&psum_lds[colv[cg]], cp);
    }
    __syncthreads();
    atomicAdd(&psum_g[tid], psum_lds[tid]);
    atomicAdd(&psum_g[tid + 512], psum_lds[tid + 512]);
}

// ---------------- gather z_q = embed[codes] ----------------
__global__ void vq_gather(const float* __restrict__ embed,
                          const float* __restrict__ codes_f,
                          float* __restrict__ outq)
{
    int idx = blockIdx.x * 256 + threadIdx.x;   // [0, 4194304)
    int b = idx >> 6;
    int c = (int)codes_f[b];
    ((float4*)outq)[idx] = ((const float4*)embed)[(c << 6) + (idx & 63)];
}

// ---------------- finalize scalars ----------------
__global__ void vq_finalize(const float* __restrict__ psum_g,
                            const float* __restrict__ counts_g,
                            const float* __restrict__ distsum_g,
                            float* __restrict__ out_s)
{
    __shared__ float s1[16], s2[16];
    int tid = threadIdx.x;           // 1024 threads
    float a = psum_g[tid] * (1.0f / 65536.0f);
    float e1 = -a * logf(a + 1e-10f);
    float h = counts_g[tid] * (1.0f / 65536.0f);
    float e2 = -h * logf(h + 1e-10f);
    #pragma unroll
    for (int off = 1; off < 64; off <<= 1) {
        e1 += __shfl_xor(e1, off);
        e2 += __shfl_xor(e2, off);
    }
    int w = tid >> 6, lane = tid & 63;
    if (lane == 0) { s1[w] = e1; s2[w] = e2; }
    __syncthreads();
    if (tid == 0) {
        float E1 = 0.0f, E2 = 0.0f;
        #pragma unroll
        for (int i = 0; i < 16; ++i) { E1 += s1[i]; E2 += s2[i]; }
        float commit = distsum_g[0] * (1.0f / 16777216.0f);
        out_s[0] = commit;
        out_s[1] = commit;
        out_s[2] = -E1 / 6.9314718055994531f;
        out_s[3] = E1;
        out_s[4] = __expf(E2);
    }
}

extern "C" void kernel_launch(void* const* d_in, const int* in_sizes, int n_in,
                              void* d_out, int out_size, void* d_ws, size_t ws_size,
                              hipStream_t stream) {
    const float* z     = (const float*)d_in[0];
    const float* embed = (const float*)d_in[1];

    float* out      = (float*)d_out;
    float* zq_out   = out;                  // 16777216
    float* codes_f  = out + 16777216;       // 65536
    float* scalars  = out + 16842752;       // 5

    float* ws        = (float*)d_ws;
    float* psum_g    = ws;                  // 1024
    float* counts_g  = ws + 1024;           // 1024
    float* e2g       = ws + 2048;           // 1024
    float* distsum_g = ws + 3072;           // 1
    char*  wsB       = (char*)d_ws + 16384; // 1 MB fp16 image

    (void)hipMemsetAsync(d_ws, 0, 3080 * sizeof(float), stream);
    vq_prep<<<128, 256, 0, stream>>>(embed, wsB);
    vq_e2<<<256, 256, 0, stream>>>(embed, e2g);
    vq_main<<<BTOT / 32, 512, 0, stream>>>(z, wsB, e2g, psum_g, counts_g,
                                           distsum_g, codes_f);
    vq_gather<<<4194304 / 256, 256, 0, stream>>>(embed, codes_f, zq_out);
    vq_finalize<<<1, 1024, 0, stream>>>(psum_g, counts_g, distsum_g, scalars);
}

// Round 7
// 337.385 us; speedup vs baseline: 1.0512x; 1.0512x over previous
//
#include <hip/hip_runtime.h>
#include <math.h>

typedef _Float16 half8 __attribute__((ext_vector_type(8)));
typedef float f32x4 __attribute__((ext_vector_type(4)));
typedef float f32x16 __attribute__((ext_vector_type(16)));

#define AS1 __attribute__((address_space(1)))
#define AS3 __attribute__((address_space(3)))

#define BTOT   65536
#define DDIM   256
#define KC     1024

// ---------------- ||e_k||^2 ----------------
__global__ void vq_e2(const float* __restrict__ embed, float* __restrict__ e2g) {
    int gt = blockIdx.x * blockDim.x + threadIdx.x;
    int k = gt >> 6;
    int lane = gt & 63;
    float4 v = *(const float4*)(embed + (size_t)k * DDIM + lane * 4);
    float s = v.x * v.x + v.y * v.y + v.z * v.z + v.w * v.w;
    #pragma unroll
    for (int off = 1; off < 64; off <<= 1) s += __shfl_xor(s, off);
    if (lane == 0) e2g[k] = s;
}

// ---------------- prep: embed -> fp16 hi/lo unit-ordered image ----------
// Unit = 2KB = 64 cols x 16 k x one piece. unit(g,kh,p) at (g*16+kh)*4096 + p*2048.
// In-unit: cg(2) x col32 x kslot(2): 16B slot at cg*1024 + ((c32*32+ks*16)^((c32&7)<<4)).
__global__ void vq_prep(const float* __restrict__ embed, char* __restrict__ wsB) {
    int id = blockIdx.x * 256 + threadIdx.x;   // 32768 total
    int c  = id >> 5;          // 0..1023
    int kh = (id >> 1) & 15;   // 0..15
    int ks = id & 1;           // 0..1
    const float* src = embed + (size_t)c * DDIM + kh * 16 + ks * 8;
    half8 hi, lo;
    #pragma unroll
    for (int j = 0; j < 8; ++j) {
        float xv = src[j];
        _Float16 hh = (_Float16)xv;
        hi[j] = hh;
        lo[j] = (_Float16)(xv - (float)hh);
    }
    int g = c >> 6, cg = (c >> 5) & 1, c32 = c & 31;
    int inner = cg * 1024 + (((c32 * 32) + ks * 16) ^ ((c32 & 7) << 4));
    size_t base = (size_t)(g * 16 + kh) * 4096;
    *(half8*)(wsB + base + inner) = hi;           // p=0 (hi)
    *(half8*)(wsB + base + 2048 + inner) = lo;    // p=1 (lo)
}

// ---------------- main fused MFMA GEMM + softmax/argmax ----------------
// 16 waves x (64r x 64c) tiles, 32x32x16 MFMA. A in LDS (64KB). Per-wave
// private 3-unit (2KB) B ring fed by global_load_lds + counted vmcnt(4).
// NO barriers in the K-loop.
__global__ __launch_bounds__(1024, 4)
void vq_main(const float* __restrict__ z, const char* __restrict__ wsB,
             const float* __restrict__ e2g, float* __restrict__ psum_g,
             float* __restrict__ counts_g, float* __restrict__ distsum_g,
             float* __restrict__ codes_f_out)
{
    __shared__ __align__(16) char ldsA[65536];   // [kh16][p2][row64][32B swz]
    __shared__ __align__(16) char ldsR[98304];   // 16 waves x 6KB rings
    // epilogue aliases (rings dead after K-loop + barrier):
    float* lmax     = (float*)ldsR;              // [64][16]
    int*   larg     = (int*)(ldsR + 4096);       // [64][16]
    float* lsum     = (float*)(ldsR + 8192);     // [64][16]
    float* rowM     = (float*)(ldsR + 12288);    // [64]
    float* rowInv   = (float*)(ldsR + 12544);    // [64]
    float* psum_lds = (float*)(ldsR + 16384);    // [1024]

    const int tid  = threadIdx.x;
    const int w    = tid >> 6;
    const int lane = tid & 63;
    const int row0 = blockIdx.x * 64;
    char* ring = ldsR + w * 6144;
    const char* gB = wsB + (size_t)w * 65536;    // wave's 32-unit stream

    // prime ring units 0,1,2 (land under A staging + barrier)
    #pragma unroll
    for (int u = 0; u < 3; ++u) {
        const char* gs = gB + u * 2048 + lane * 16;
        char* ld = ring + u * 2048 + lane * 16;
        __builtin_amdgcn_global_load_lds((AS1 const void*)gs, (AS3 void*)ld, 16, 0, 0);
        __builtin_amdgcn_global_load_lds((AS1 const void*)(gs + 1024),
                                         (AS3 void*)(ld + 1024), 16, 0, 0);
    }

    // ---- A staging: 64 rows -> fp16 hi/lo swizzled; also sum ||z||^2 ----
    {
        const int ar = tid >> 4;     // row 0..63
        const int kh = tid & 15;     // 16-float k-part
        const float* src = z + (size_t)(row0 + ar) * DDIM + kh * 16;
        float x[16];
        #pragma unroll
        for (int j = 0; j < 4; ++j) {
            f32x4 v = *(const f32x4*)(src + 4 * j);
            x[4*j] = v[0]; x[4*j+1] = v[1]; x[4*j+2] = v[2]; x[4*j+3] = v[3];
        }
        float zsq = 0.f;
        #pragma unroll
        for (int j = 0; j < 16; ++j) zsq = fmaf(x[j], x[j], zsq);
        #pragma unroll
        for (int off = 1; off < 64; off <<= 1) zsq += __shfl_xor(zsq, off);
        if (lane == 0) atomicAdd(distsum_g, zsq);
        #pragma unroll
        for (int ks = 0; ks < 2; ++ks) {
            half8 hi, lo;
            #pragma unroll
            for (int j = 0; j < 8; ++j) {
                float xv = x[ks * 8 + j];
                _Float16 hh = (_Float16)xv;
                hi[j] = hh;
                lo[j] = (_Float16)(xv - (float)hh);
            }
            int inner = ((ar * 32 + ks * 16) ^ ((ar & 7) << 4)) ^ ((kh & 3) << 5);
            *(half8*)(ldsA + kh * 4096 + inner) = hi;          // p=0
            *(half8*)(ldsA + kh * 4096 + 2048 + inner) = lo;   // p=1
        }
    }
    __syncthreads();

    f32x16 acc[2][2];
    #pragma unroll
    for (int rt = 0; rt < 2; ++rt)
        #pragma unroll
        for (int cg = 0; cg < 2; ++cg)
            #pragma unroll
            for (int i = 0; i < 16; ++i) acc[rt][cg][i] = 0.f;

    // fragment offset: row/col=(lane&31), kslot=lane>>5, bank-XOR-swizzled
    const int fOffB = (((lane & 31) * 32) + ((lane >> 5) * 16)) ^ ((lane & 7) << 4);

    // ---- K-loop: 16 kh steps x {bH unit, bL unit}; barrier-free ----
    #pragma unroll
    for (int kh = 0; kh < 16; ++kh) {
        const int u = kh * 2;
        const int fOffA = fOffB ^ ((kh & 3) << 5);
        // ===== unit u (bH) =====
        if (kh < 15) asm volatile("s_waitcnt vmcnt(4)" ::: "memory");
        else         asm volatile("s_waitcnt vmcnt(2)" ::: "memory");
        half8 aH0 = *(const half8*)(ldsA + kh * 4096 + fOffA);
        half8 aH1 = *(const half8*)(ldsA + kh * 4096 + 1024 + fOffA);
        half8 aL0 = *(const half8*)(ldsA + kh * 4096 + 2048 + fOffA);
        half8 aL1 = *(const half8*)(ldsA + kh * 4096 + 3072 + fOffA);
        half8 b0 = *(const half8*)(ring + (u % 3) * 2048 + fOffB);
        half8 b1 = *(const half8*)(ring + (u % 3) * 2048 + 1024 + fOffB);
        asm volatile("s_waitcnt lgkmcnt(0)" ::: "memory");
        if (u + 3 < 32) {   // refill freed slot
            const char* gs = gB + (u + 3) * 2048 + lane * 16;
            char* ld = ring + ((u + 3) % 3) * 2048 + lane * 16;
            __builtin_amdgcn_global_load_lds((AS1 const void*)gs, (AS3 void*)ld, 16, 0, 0);
            __builtin_amdgcn_global_load_lds((AS1 const void*)(gs + 1024),
                                             (AS3 void*)(ld + 1024), 16, 0, 0);
        }
        acc[0][0] = __builtin_amdgcn_mfma_f32_32x32x16_f16(aH0, b0, acc[0][0], 0, 0, 0);
        acc[1][0] = __builtin_amdgcn_mfma_f32_32x32x16_f16(aH1, b0, acc[1][0], 0, 0, 0);
        acc[0][1] = __builtin_amdgcn_mfma_f32_32x32x16_f16(aH0, b1, acc[0][1], 0, 0, 0);
        acc[1][1] = __builtin_amdgcn_mfma_f32_32x32x16_f16(aH1, b1, acc[1][1], 0, 0, 0);
        acc[0][0] = __builtin_amdgcn_mfma_f32_32x32x16_f16(aL0, b0, acc[0][0], 0, 0, 0);
        acc[1][0] = __builtin_amdgcn_mfma_f32_32x32x16_f16(aL1, b0, acc[1][0], 0, 0, 0);
        acc[0][1] = __builtin_amdgcn_mfma_f32_32x32x16_f16(aL0, b1, acc[0][1], 0, 0, 0);
        acc[1][1] = __builtin_amdgcn_mfma_f32_32x32x16_f16(aL1, b1, acc[1][1], 0, 0, 0);
        // ===== unit u+1 (bL) =====
        if (kh < 15) asm volatile("s_waitcnt vmcnt(4)" ::: "memory");
        else         asm volatile("s_waitcnt vmcnt(0)" ::: "memory");
        half8 c0 = *(const half8*)(ring + ((u + 1) % 3) * 2048 + fOffB);
        half8 c1 = *(const half8*)(ring + ((u + 1) % 3) * 2048 + 1024 + fOffB);
        asm volatile("s_waitcnt lgkmcnt(0)" ::: "memory");
        if (u + 4 < 32) {
            const char* gs = gB + (u + 4) * 2048 + lane * 16;
            char* ld = ring + ((u + 4) % 3) * 2048 + lane * 16;
            __builtin_amdgcn_global_load_lds((AS1 const void*)gs, (AS3 void*)ld, 16, 0, 0);
            __builtin_amdgcn_global_load_lds((AS1 const void*)(gs + 1024),
                                             (AS3 void*)(ld + 1024), 16, 0, 0);
        }
        acc[0][0] = __builtin_amdgcn_mfma_f32_32x32x16_f16(aH0, c0, acc[0][0], 0, 0, 0);
        acc[1][0] = __builtin_amdgcn_mfma_f32_32x32x16_f16(aH1, c0, acc[1][0], 0, 0, 0);
        acc[0][1] = __builtin_amdgcn_mfma_f32_32x32x16_f16(aH0, c1, acc[0][1], 0, 0, 0);
        acc[1][1] = __builtin_amdgcn_mfma_f32_32x32x16_f16(aH1, c1, acc[1][1], 0, 0, 0);
    }
    __syncthreads();   // all rings dead -> epilogue may reuse ldsR

    // ---- epilogue ----
    // C/D 32x32 layout: col = lane&31, row = (i&3) + 8*(i>>2) + 4*(lane>>5)
    const int half = lane >> 5;
    const int c0i = w * 64 + (lane & 31);
    const int c1i = c0i + 32;
    float e2v0 = e2g[c0i];
    float e2v1 = e2g[c1i];
    psum_lds[tid] = 0.f;

    // pass 1: per-wave row max/argmax
    #pragma unroll
    for (int rt = 0; rt < 2; ++rt) {
        #pragma unroll
        for (int i = 0; i < 16; ++i) {
            float l0 = fmaf(2.f, acc[rt][0][i], -e2v0);
            float l1 = fmaf(2.f, acc[rt][1][i], -e2v1);
            float m; int am;
            if (l1 > l0) { m = l1; am = c1i; } else { m = l0; am = c0i; }
            #pragma unroll
            for (int off = 1; off < 32; off <<= 1) {
                float om = __shfl_xor(m, off);
                int   oa = __shfl_xor(am, off);
                if (om > m || (om == m && oa < am)) { m = om; am = oa; }
            }
            if ((lane & 31) == 0) {
                int r = rt * 32 + (i & 3) + 8 * (i >> 2) + 4 * half;
                lmax[r * 16 + w] = m; larg[r * 16 + w] = am;
            }
        }
    }
    __syncthreads();
    // pass 2: cross-wave reduce -> codes, counts, -sum(max logit)
    if (tid < 64) {
        float M = -INFINITY; int A = 0x7fffffff;
        #pragma unroll
        for (int ww = 0; ww < 16; ++ww) {
            float mm = lmax[tid * 16 + ww]; int aa = larg[tid * 16 + ww];
            if (mm > M || (mm == M && aa < A)) { M = mm; A = aa; }
        }
        rowM[tid] = M;
        codes_f_out[row0 + tid] = (float)A;
        atomicAdd(&counts_g[A], 1.0f);
        float negm = -M;
        #pragma unroll
        for (int off = 1; off < 64; off <<= 1) negm += __shfl_xor(negm, off);
        if (tid == 0) atomicAdd(distsum_g, negm);
    }
    __syncthreads();
    // pass 3: exp + per-wave row sums
    #pragma unroll
    for (int rt = 0; rt < 2; ++rt) {
        #pragma unroll
        for (int i = 0; i < 16; ++i) {
            int r = rt * 32 + (i & 3) + 8 * (i >> 2) + 4 * half;
            float M = rowM[r];
            float e0 = __expf(fmaf(2.f, acc[rt][0][i], -e2v0) - M);
            float e1 = __expf(fmaf(2.f, acc[rt][1][i], -e2v1) - M);
            acc[rt][0][i] = e0; acc[rt][1][i] = e1;
            float ss = e0 + e1;
            #pragma unroll
            for (int off = 1; off < 32; off <<= 1) ss += __shfl_xor(ss, off);
            if ((lane & 31) == 0) lsum[r * 16 + w] = ss;
        }
    }
    __syncthreads();
    // pass 4: row denominators
    if (tid < 64) {
        float S = 0.f;
        #pragma unroll
        for (int ww = 0; ww < 16; ++ww) S += lsum[tid * 16 + ww];
        rowInv[tid] = 1.0f / S;
    }
    __syncthreads();
    // pass 5: per-code prob sums
    {
        float cp0 = 0.f, cp1 = 0.f;
        #pragma unroll
        for (int rt = 0; rt < 2; ++rt) {
            #pragma unroll
            for (int i = 0; i < 16; ++i) {
                int r = rt * 32 + (i & 3) + 8 * (i >> 2) + 4 * half;
                float inv = rowInv[r];
                cp0 = fmaf(acc[rt][0][i], inv, cp0);
                cp1 = fmaf(acc[rt][1][i], inv, cp1);
            }
        }
        atomicAdd(&psum_lds[c0i], cp0);
        atomicAdd(&psum_lds[c1i], cp1);
    }
    __syncthreads();
    atomicAdd(&psum_g[tid], psum_lds[tid]);
}

// ---------------- gather z_q = embed[codes] ----------------
__global__ void vq_gather(const float* __restrict__ embed,
                          const float* __restrict__ codes_f,
                          float* __restrict__ outq)
{
    int idx = blockIdx.x * 256 + threadIdx.x;   // [0, 4194304)
    int b = idx >> 6;
    int c = (int)codes_f[b];
    ((float4*)outq)[idx] = ((const float4*)embed)[(c << 6) + (idx & 63)];
}

// ---------------- finalize scalars ----------------
__global__ void vq_finalize(const float* __restrict__ psum_g,
                            const float* __restrict__ counts_g,
                            const float* __restrict__ distsum_g,
                            float* __restrict__ out_s)
{
    __shared__ float s1[16], s2[16];
    int tid = threadIdx.x;           // 1024 threads
    float a = psum_g[tid] * (1.0f / 65536.0f);
    float e1 = -a * logf(a + 1e-10f);
    float h = counts_g[tid] * (1.0f / 65536.0f);
    float e2 = -h * logf(h + 1e-10f);
    #pragma unroll
    for (int off = 1; off < 64; off <<= 1) {
        e1 += __shfl_xor(e1, off);
        e2 += __shfl_xor(e2, off);
    }
    int w = tid >> 6, lane = tid & 63;
    if (lane == 0) { s1[w] = e1; s2[w] = e2; }
    __syncthreads();
    if (tid == 0) {
        float E1 = 0.0f, E2 = 0.0f;
        #pragma unroll
        for (int i = 0; i < 16; ++i) { E1 += s1[i]; E2 += s2[i]; }
        float commit = distsum_g[0] * (1.0f / 16777216.0f);
        out_s[0] = commit;
        out_s[1] = commit;
        out_s[2] = -E1 / 6.9314718055994531f;
        out_s[3] = E1;
        out_s[4] = __expf(E2);
    }
}

extern "C" void kernel_launch(void* const* d_in, const int* in_sizes, int n_in,
                              void* d_out, int out_size, void* d_ws, size_t ws_size,
                              hipStream_t stream) {
    const float* z     = (const float*)d_in[0];
    const float* embed = (const float*)d_in[1];

    float* out      = (float*)d_out;
    float* zq_out   = out;                  // 16777216
    float* codes_f  = out + 16777216;       // 65536
    float* scalars  = out + 16842752;       // 5

    float* ws        = (float*)d_ws;
    float* psum_g    = ws;                  // 1024
    float* counts_g  = ws + 1024;           // 1024
    float* e2g       = ws + 2048;           // 1024
    float* distsum_g = ws + 3072;           // 1
    char*  wsB       = (char*)d_ws + 16384; // 1 MB fp16 unit image

    (void)hipMemsetAsync(d_ws, 0, 3080 * sizeof(float), stream);
    vq_prep<<<128, 256, 0, stream>>>(embed, wsB);
    vq_e2<<<256, 256, 0, stream>>>(embed, e2g);
    vq_main<<<BTOT / 64, 1024, 0, stream>>>(z, wsB, e2g, psum_g, counts_g,
                                            distsum_g, codes_f);
    vq_gather<<<4194304 / 256, 256, 0, stream>>>(embed, codes_f, zq_out);
    vq_finalize<<<1, 1024, 0, stream>>>(psum_g, counts_g, distsum_g, scalars);
}

// Round 10
// 323.701 us; speedup vs baseline: 1.0957x; 1.0423x over previous
//
#include <hip/hip_runtime.h>
#include <math.h>

typedef _Float16 half8 __attribute__((ext_vector_type(8)));
typedef float f32x4 __attribute__((ext_vector_type(4)));

#define AS1 __attribute__((address_space(1)))
#define AS3 __attribute__((address_space(3)))

#define BTOT   65536
#define DDIM   256
#define KC     1024

// ---------------- ||e_k||^2 ----------------
__global__ void vq_e2(const float* __restrict__ embed, float* __restrict__ e2g) {
    int gt = blockIdx.x * blockDim.x + threadIdx.x;
    int k = gt >> 6;
    int lane = gt & 63;
    float4 v = *(const float4*)(embed + (size_t)k * DDIM + lane * 4);
    float s = v.x * v.x + v.y * v.y + v.z * v.z + v.w * v.w;
    #pragma unroll
    for (int off = 1; off < 64; off <<= 1) s += __shfl_xor(s, off);
    if (lane == 0) e2g[k] = s;
}

// ---------------- prep: embed -> fp16 hi/lo pre-swizzled image (R3) ------
// 64 chunks of 16384B. chunk = kc*8 + p*4 + q  (kc 0..7, p: 0=hi 1=lo, q: col
// quarter). Within chunk: local col cl(0..255)*64B; 16B slot s at
// (s ^ ((cl>>1)&3))*16.
__global__ void vq_prep(const float* __restrict__ embed, char* __restrict__ wsB) {
    int id = blockIdx.x * 256 + threadIdx.x;   // 32768 total
    int c  = id >> 5;          // 0..1023
    int kc = (id >> 2) & 7;    // 0..7
    int s  = id & 3;           // 0..3
    const float* src = embed + (size_t)c * DDIM + kc * 32 + s * 8;
    half8 hi, lo;
    #pragma unroll
    for (int j = 0; j < 8; ++j) {
        float xv = src[j];
        _Float16 hh = (_Float16)xv;
        hi[j] = hh;
        lo[j] = (_Float16)(xv - (float)hh);
    }
    int q = c >> 8, cl = c & 255;
    int inner = cl * 64 + ((s ^ ((cl >> 1) & 3)) << 4);
    *(half8*)(wsB + (size_t)(kc * 8 + q) * 16384 + inner) = hi;
    *(half8*)(wsB + (size_t)(kc * 8 + 4 + q) * 16384 + inner) = lo;
}

// ---------------- main fused MFMA GEMM + softmax/argmax ----------------
// 512 thr / 8 waves; block owns 32 rows x 1024 cols. A in LDS (32KB).
// B: block-wide 3 x 16KB stage ring via global_load_lds, counted vmcnt(2),
// one barrier per stage. LDS = 80KB -> 2 blocks/CU for cross-block overlap.
// RACE FIX (R10): stage boundary must drain lgkmcnt BEFORE the barrier —
// the prefetch issued after barrier s overwrites the slot read at stage s-1,
// and hipcc can sink register-only MFMAs (with their lgkmcnt waits) past an
// inline-asm barrier ("memory" doesn't order them — rule #18). lgkmcnt(0)
// in the barrier asm + sched_barrier(0) fencing makes reads provably
// complete before the overwrite can issue.
__global__ __launch_bounds__(512, 4)
void vq_main(const float* __restrict__ z, const char* __restrict__ wsB,
             const float* __restrict__ e2g, float* __restrict__ psum_g,
             float* __restrict__ counts_g, float* __restrict__ distsum_g,
             float* __restrict__ codes_f_out)
{
    // A: [kc(8)][p(2)][row(32)][slot(4, xor-swizzled)] = 32KB
    __shared__ __align__(16) char ldsA[32768];
    __shared__ __align__(16) char ldsB[49152];    // 3 x 16KB stage ring
    // epilogue aliases (ldsA dead after K-loop):
    float* lmax     = (float*)ldsA;               // [32][8] 1KB
    int*   larg     = (int*)(ldsA + 1024);        // [32][8] 1KB
    float* lsum     = (float*)(ldsA + 2048);      // [32][8] 1KB
    float* rowM     = (float*)(ldsA + 3072);      // [32]
    float* rowInv   = (float*)(ldsA + 3200);      // [32]
    float* psum_lds = (float*)(ldsA + 4096);      // [1024] 4KB

    const int tid  = threadIdx.x;
    const int w    = tid >> 6;
    const int lane = tid & 63;
    const int row0 = blockIdx.x * 32;
    // swizzled fragment bases (slot = (lane>>4) ^ ((lane>>1)&3)):
    const int swz   = ((lane >> 4) ^ ((lane >> 1) & 3)) << 4;
    const int aBase = (lane & 15) * 64 + swz;
    const int bBase = w * 2048 + (lane & 15) * 64 + swz;

    // issue stages 0,1 (land during A staging; drained by the syncthreads)
    #pragma unroll
    for (int ps = 0; ps < 2; ++ps) {
        const char* gs = wsB + (size_t)ps * 16384 + tid * 16;
        char* ld = ldsB + ps * 16384 + tid * 16;
        __builtin_amdgcn_global_load_lds((AS1 const void*)gs, (AS3 void*)ld, 16, 0, 0);
        __builtin_amdgcn_global_load_lds((AS1 const void*)(gs + 8192),
                                         (AS3 void*)(ld + 8192), 16, 0, 0);
    }

    // ---- A staging: 32 rows of z -> fp16 hi/lo swizzled in LDS ----
    {
        const int ar = tid >> 4;     // row 0..31
        const int kp = tid & 15;     // 16-float k-part
        const float* src = z + (size_t)(row0 + ar) * DDIM + kp * 16;
        float x[16];
        #pragma unroll
        for (int j = 0; j < 4; ++j) {
            f32x4 v = *(const f32x4*)(src + 4 * j);
            x[4*j] = v[0]; x[4*j+1] = v[1]; x[4*j+2] = v[2]; x[4*j+3] = v[3];
        }
        float zsq = 0.f;
        #pragma unroll
        for (int j = 0; j < 16; ++j) zsq = fmaf(x[j], x[j], zsq);
        #pragma unroll
        for (int off = 1; off < 64; off <<= 1) zsq += __shfl_xor(zsq, off);
        if (lane == 0) atomicAdd(distsum_g, zsq);   // Σ||z||^2 (4 rows/wave)
        const int kc = kp >> 1;
        #pragma unroll
        for (int jj = 0; jj < 2; ++jj) {
            int s = (kp & 1) * 2 + jj;
            half8 hi, lo;
            #pragma unroll
            for (int j = 0; j < 8; ++j) {
                float xv = x[jj * 8 + j];
                _Float16 hh = (_Float16)xv;
                hi[j] = hh;
                lo[j] = (_Float16)(xv - (float)hh);
            }
            int off = kc * 4096 + ar * 64 + ((s ^ ((ar >> 1) & 3)) << 4);
            *(half8*)(ldsA + off) = hi;            // p=0
            *(half8*)(ldsA + 2048 + off) = lo;     // p=1
        }
    }
    __syncthreads();   // A visible; stages 0,1 drained (one-time full drain)

    f32x4 acc[2][8];
    #pragma unroll
    for (int rt = 0; rt < 2; ++rt)
        #pragma unroll
        for (int cg = 0; cg < 8; ++cg)
            acc[rt][cg] = (f32x4){0.f, 0.f, 0.f, 0.f};

    half8 aHi[2], aLo[2];

    // ---- K-loop: 64 stages, s = kc*8 + p*4 + q; counted vmcnt, 1 barrier ----
    // Top-of-stage outstanding loads: {s, s+1} = 4 -> vmcnt(2) drains stage s.
    // lgkmcnt(0): all of THIS wave's LDS reads (stage s-1) complete before the
    // barrier -> slot (s-1)%3 is safe to overwrite by the s+2 prefetch issued
    // after the barrier. sched_barrier(0) pins MFMAs/ds_reads to their stage.
    #pragma unroll
    for (int s = 0; s < 64; ++s) {
        const int kc = s >> 3, p = (s >> 2) & 1, q = s & 3;
        __builtin_amdgcn_sched_barrier(0);
        if (s < 63) asm volatile("s_waitcnt vmcnt(2) lgkmcnt(0)\n\ts_barrier" ::: "memory");
        else        asm volatile("s_waitcnt vmcnt(0) lgkmcnt(0)\n\ts_barrier" ::: "memory");
        __builtin_amdgcn_sched_barrier(0);
        if (s + 2 < 64) {   // prefetch into ring slot freed at the barrier
            const char* gs = wsB + (size_t)(s + 2) * 16384 + tid * 16;
            char* ld = ldsB + ((s + 2) % 3) * 16384 + tid * 16;
            __builtin_amdgcn_global_load_lds((AS1 const void*)gs, (AS3 void*)ld, 16, 0, 0);
            __builtin_amdgcn_global_load_lds((AS1 const void*)(gs + 8192),
                                             (AS3 void*)(ld + 8192), 16, 0, 0);
        }
        if (p == 0 && q == 0) {
            aHi[0] = *(const half8*)(ldsA + kc * 4096 + aBase);
            aHi[1] = *(const half8*)(ldsA + kc * 4096 + 1024 + aBase);
            aLo[0] = *(const half8*)(ldsA + kc * 4096 + 2048 + aBase);
            aLo[1] = *(const half8*)(ldsA + kc * 4096 + 3072 + aBase);
        }
        const char* bb = ldsB + (s % 3) * 16384 + bBase;
        #pragma unroll
        for (int ct = 0; ct < 2; ++ct) {
            half8 bf = *(const half8*)(bb + ct * 1024);
            const int cg = q * 2 + ct;
            // per-acc order: hi*bH, lo*bH (p=0), then hi*bL (p=1) — matches
            // verified R2-R4 numerics.
            acc[0][cg] = __builtin_amdgcn_mfma_f32_16x16x32_f16(aHi[0], bf, acc[0][cg], 0, 0, 0);
            acc[1][cg] = __builtin_amdgcn_mfma_f32_16x16x32_f16(aHi[1], bf, acc[1][cg], 0, 0, 0);
            if (p == 0) {
                acc[0][cg] = __builtin_amdgcn_mfma_f32_16x16x32_f16(aLo[0], bf, acc[0][cg], 0, 0, 0);
                acc[1][cg] = __builtin_amdgcn_mfma_f32_16x16x32_f16(aLo[1], bf, acc[1][cg], 0, 0, 0);
            }
        }
    }
    __syncthreads();   // ring reads done; ldsA dead -> epilogue reuse

    // ---- epilogue ----
    // wave w cols: cg -> (cg>>1)*256 + w*32 + (cg&1)*16 + (lane&15)
    // C/D layout: col = lane&15, row = rt*16 + (lane>>4)*4 + i
    int colv[8];
    float e2v[8];
    #pragma unroll
    for (int cg = 0; cg < 8; ++cg) {
        colv[cg] = (cg >> 1) * 256 + w * 32 + (cg & 1) * 16 + (lane & 15);
        e2v[cg] = e2g[colv[cg]];
    }
    psum_lds[tid] = 0.f;
    psum_lds[tid + 512] = 0.f;
    // pass 1: per-wave local max/argmax per row
    #pragma unroll
    for (int rt = 0; rt < 2; ++rt) {
        #pragma unroll
        for (int i = 0; i < 4; ++i) {
            float m = -INFINITY; int am = 0x7fffffff;
            #pragma unroll
            for (int cg = 0; cg < 8; ++cg) {
                float l = fmaf(2.f, acc[rt][cg][i], -e2v[cg]);
                if (l > m) { m = l; am = colv[cg]; }
            }
            #pragma unroll
            for (int off = 1; off < 16; off <<= 1) {
                float om = __shfl_xor(m, off);
                int   oa = __shfl_xor(am, off);
                if (om > m || (om == m && oa < am)) { m = om; am = oa; }
            }
            if ((lane & 15) == 0) {
                int r = rt * 16 + ((lane >> 4) << 2) + i;
                lmax[r * 8 + w] = m; larg[r * 8 + w] = am;
            }
        }
    }
    __syncthreads();
    // pass 2: cross-wave reduce; codes, counts, -Σ(max logit)
    if (tid < 32) {
        float M = -INFINITY; int A = 0x7fffffff;
        #pragma unroll
        for (int ww = 0; ww < 8; ++ww) {
            float mm = lmax[tid * 8 + ww]; int aa = larg[tid * 8 + ww];
            if (mm > M || (mm == M && aa < A)) { M = mm; A = aa; }
        }
        rowM[tid] = M;
        codes_f_out[row0 + tid] = (float)A;
        atomicAdd(&counts_g[A], 1.0f);
        float negm = -M;
        #pragma unroll
        for (int off = 1; off < 32; off <<= 1) negm += __shfl_xor(negm, off);
        if (tid == 0) atomicAdd(distsum_g, negm);
    }
    __syncthreads();
    // pass 3: exp and per-wave row sums
    #pragma unroll
    for (int rt = 0; rt < 2; ++rt) {
        #pragma unroll
        for (int i = 0; i < 4; ++i) {
            const int r = rt * 16 + ((lane >> 4) << 2) + i;
            float M = rowM[r];
            float ss = 0.f;
            #pragma unroll
            for (int cg = 0; cg < 8; ++cg) {
                float e = __expf(fmaf(2.f, acc[rt][cg][i], -e2v[cg]) - M);
                acc[rt][cg][i] = e;
                ss += e;
            }
            #pragma unroll
            for (int off = 1; off < 16; off <<= 1) ss += __shfl_xor(ss, off);
            if ((lane & 15) == 0) lsum[r * 8 + w] = ss;
        }
    }
    __syncthreads();
    // pass 4: row denominators
    if (tid < 32) {
        float S = 0.f;
        #pragma unroll
        for (int ww = 0; ww < 8; ++ww) S += lsum[tid * 8 + ww];
        rowInv[tid] = 1.0f / S;
    }
    __syncthreads();
    // pass 5: per-code prob sums
    #pragma unroll
    for (int cg = 0; cg < 8; ++cg) {
        float cp = 0.f;
        #pragma unroll
        for (int rt = 0; rt < 2; ++rt)
            #pragma unroll
            for (int i = 0; i < 4; ++i)
                cp = fmaf(acc[rt][cg][i], rowInv[rt * 16 + ((lane >> 4) << 2) + i], cp);
        atomicAdd(&psum_lds[colv[cg]], cp);
    }
    __syncthreads();
    atomicAdd(&psum_g[tid], psum_lds[tid]);
    atomicAdd(&psum_g[tid + 512], psum_lds[tid + 512]);
}

// ---------------- gather z_q = embed[codes] ----------------
__global__ void vq_gather(const float* __restrict__ embed,
                          const float* __restrict__ codes_f,
                          float* __restrict__ outq)
{
    int idx = blockIdx.x * 256 + threadIdx.x;   // [0, 4194304)
    int b = idx >> 6;
    int c = (int)codes_f[b];
    ((float4*)outq)[idx] = ((const float4*)embed)[(c << 6) + (idx & 63)];
}

// ---------------- finalize scalars ----------------
__global__ void vq_finalize(const float* __restrict__ psum_g,
                            const float* __restrict__ counts_g,
                            const float* __restrict__ distsum_g,
                            float* __restrict__ out_s)
{
    __shared__ float s1[16], s2[16];
    int tid = threadIdx.x;           // 1024 threads
    float a = psum_g[tid] * (1.0f / 65536.0f);
    float e1 = -a * logf(a + 1e-10f);
    float h = counts_g[tid] * (1.0f / 65536.0f);
    float e2 = -h * logf(h + 1e-10f);
    #pragma unroll
    for (int off = 1; off < 64; off <<= 1) {
        e1 += __shfl_xor(e1, off);
        e2 += __shfl_xor(e2, off);
    }
    int w = tid >> 6, lane = tid & 63;
    if (lane == 0) { s1[w] = e1; s2[w] = e2; }
    __syncthreads();
    if (tid == 0) {
        float E1 = 0.0f, E2 = 0.0f;
        #pragma unroll
        for (int i = 0; i < 16; ++i) { E1 += s1[i]; E2 += s2[i]; }
        float commit = distsum_g[0] * (1.0f / 16777216.0f);
        out_s[0] = commit;
        out_s[1] = commit;
        out_s[2] = -E1 / 6.9314718055994531f;
        out_s[3] = E1;
        out_s[4] = __expf(E2);
    }
}

extern "C" void kernel_launch(void* const* d_in, const int* in_sizes, int n_in,
                              void* d_out, int out_size, void* d_ws, size_t ws_size,
                              hipStream_t stream) {
    const float* z     = (const float*)d_in[0];
    const float* embed = (const float*)d_in[1];

    float* out      = (float*)d_out;
    float* zq_out   = out;                  // 16777216
    float* codes_f  = out + 16777216;       // 65536
    float* scalars  = out + 16842752;       // 5

    float* ws        = (float*)d_ws;
    float* psum_g    = ws;                  // 1024
    float* counts_g  = ws + 1024;           // 1024
    float* e2g       = ws + 2048;           // 1024
    float* distsum_g = ws + 3072;           // 1
    char*  wsB       = (char*)d_ws + 16384; // 1 MB fp16 image

    (void)hipMemsetAsync(d_ws, 0, 3080 * sizeof(float), stream);
    vq_prep<<<128, 256, 0, stream>>>(embed, wsB);
    vq_e2<<<256, 256, 0, stream>>>(embed, e2g);
    vq_main<<<BTOT / 32, 512, 0, stream>>>(z, wsB, e2g, psum_g, counts_g,
                                           distsum_g, codes_f);
    vq_gather<<<4194304 / 256, 256, 0, stream>>>(embed, codes_f, zq_out);
    vq_finalize<<<1, 1024, 0, stream>>>(psum_g, counts_g, distsum_g, scalars);
}